// Round 11
// baseline (1245.354 us; speedup 1.0000x reference)
//
#include <hip/hip_runtime.h>
#include <hip/hip_fp16.h>
#include <hip/hip_cooperative_groups.h>

namespace cg = cooperative_groups;

typedef _Float16 half8 __attribute__((ext_vector_type(8)));
typedef float f32x4 __attribute__((ext_vector_type(4)));
typedef float f32x16 __attribute__((ext_vector_type(16)));

#define HID 128
#define NDIM 16
#define NCONV 8

static __device__ __forceinline__ half8 load_h8(const _Float16* p) {
    return *(const half8*)p;
}

// ---------------- weight prep ----------------
// WABT[l] rows j<128: W1A_T[j][k]=W1[k][j]-W1[128+k][j]; rows 128+j: W1B_T[j][k]=W1[128+k][j]
// W2T[l][j][k] = W2[k][j].  Tails: dWT[j][k]=dW[k*16+j]; biasAB[l][0:128]=b1_l, [128:256]=0;
// deg[] zeroed (CSR count runs next dispatch).
__global__ void prep_weights(const float* __restrict__ W1, const float* __restrict__ W2,
                             const float* __restrict__ dW, const float* __restrict__ b1,
                             _Float16* __restrict__ WABT, _Float16* __restrict__ W2T,
                             _Float16* __restrict__ dWT, float* __restrict__ biasAB,
                             int* __restrict__ deg, int n) {
    int idx = blockIdx.x * blockDim.x + threadIdx.x;
    int total = NCONV * HID * HID;
    if (idx < total) {
        int l = idx / (HID * HID);
        int r = idx % (HID * HID);
        int k = r / HID;        // slow: input row
        int j = r % HID;        // fast: input col -> coalesced loads
        const float* w1 = W1 + (size_t)l * 2 * HID * HID;
        float top = w1[k * HID + j];
        float bot = w1[(HID + k) * HID + j];
        _Float16* wab = WABT + (size_t)l * 2 * HID * HID;
        wab[j * HID + k] = (_Float16)(top - bot);
        wab[(HID + j) * HID + k] = (_Float16)bot;
        const float* w2 = W2 + (size_t)l * HID * HID;
        W2T[(size_t)l * HID * HID + j * HID + k] = (_Float16)w2[k * HID + j];
    } else if (idx < total + 16 * HID) {
        int r = idx - total;
        int j = r / HID;        // 0..15
        int k = r % HID;
        dWT[j * HID + k] = (_Float16)dW[k * NDIM + j];
    } else if (idx < total + 16 * HID + NCONV * 256) {
        int r = idx - total - 16 * HID;
        int l = r >> 8;
        int c = r & 255;
        biasAB[l * 256 + c] = (c < HID) ? b1[l * HID + c] : 0.f;
    } else if (idx < total + 16 * HID + NCONV * 256 + n) {
        deg[idx - total - 16 * HID - NCONV * 256] = 0;
    }
}

// ---------------- enc fold: layer 4 gets (E@W1A, E@W1B) and (eb@W1A+b1, eb@W1B) ----------------
// (h@E+eb)@W1 + b1 == h@(E@W1) + (eb@W1 + b1): enc_fc disappears as a dispatch.
__global__ void enc_fold(const float* __restrict__ W1, const float* __restrict__ eW,
                         const float* __restrict__ eb, const float* __restrict__ b1,
                         _Float16* __restrict__ WABT, float* __restrict__ biasAB) {
    int idx = blockIdx.x * blockDim.x + threadIdx.x;
    const float* w1 = W1 + (size_t)4 * 2 * HID * HID;   // layer 4
    _Float16* wab = WABT + (size_t)4 * 2 * HID * HID;
    if (idx < HID * HID) {                 // A-part: WABT4[j][k] = sum_q eW[k][q]*(W1[q][j]-W1[128+q][j])
        int k = idx / HID;
        int j = idx % HID;
        float acc = 0.f;
        for (int q = 0; q < HID; q++)
            acc += eW[k * HID + q] * (w1[q * HID + j] - w1[(HID + q) * HID + j]);
        wab[j * HID + k] = (_Float16)acc;
    } else if (idx < 2 * HID * HID) {      // B-part: WABT4[128+j][k] = sum_q eW[k][q]*W1[128+q][j]
        int r = idx - HID * HID;
        int k = r / HID;
        int j = r % HID;
        float acc = 0.f;
        for (int q = 0; q < HID; q++)
            acc += eW[k * HID + q] * w1[(HID + q) * HID + j];
        wab[(HID + j) * HID + k] = (_Float16)acc;
    } else if (idx < 2 * HID * HID + 256) {  // biases
        int c = idx - 2 * HID * HID;
        if (c < HID) {
            float acc = b1[4 * HID + c];
            for (int q = 0; q < HID; q++)
                acc += eb[q] * (w1[q * HID + c] - w1[(HID + q) * HID + c]);
            biasAB[4 * 256 + c] = acc;
        } else {
            int j = c - HID;
            float acc = 0.f;
            for (int q = 0; q < HID; q++)
                acc += eb[q] * w1[(HID + q) * HID + j];
            biasAB[4 * 256 + c] = acc;
        }
    }
}

// ---------------- node embedding (time emb fused) + CSR degree count ----------------
__global__ __launch_bounds__(256) void node_emb_count(const float* __restrict__ x,
                                                      const float* __restrict__ t,
                                                      const float* __restrict__ tpW,
                                                      const float* __restrict__ tpb,
                                                      const float* __restrict__ W,
                                                      const float* __restrict__ b,
                                                      const int* __restrict__ ei,
                                                      int* __restrict__ deg,
                                                      _Float16* __restrict__ h16,
                                                      int n, int E) {
    __shared__ float sc[64];
    __shared__ float temb[NDIM];
    int tid = threadIdx.x;
    float tv = t[0];
    if (tid < 32) {
        float f = expf(-4.0f + 8.0f * (float)tid / 31.0f);
        sc[tid] = sinf(tv * f);
        sc[32 + tid] = cosf(tv * f);
    }
    __syncthreads();
    if (tid < 16) {
        float acc = tpb[tid];
        for (int k = 0; k < 64; k++) acc += sc[k] * tpW[k * NDIM + tid];
        temb[tid] = acc;
    }
    __syncthreads();
    int j = tid & 127;
    int half = tid >> 7;
    for (int base = blockIdx.x * 2; base < n; base += gridDim.x * 2) {
        int node = base + half;
        if (node < n) {
            const float* xr = x + (size_t)node * NDIM;
            float acc = b[j];
            #pragma unroll
            for (int d = 0; d < NDIM; d++) acc += (xr[d] + temb[d]) * W[d * HID + j];
            h16[(size_t)node * HID + j] = (_Float16)acc;
        }
    }
    // degree count (deg zeroed by prep_weights, previous dispatch)
    int gtid = blockIdx.x * blockDim.x + tid;
    int gsz = gridDim.x * blockDim.x;
    for (int e = gtid; e < E; e += gsz) atomicAdd(&deg[ei[E + e]], 1);
}

// ---------------- CSR scan / fill ----------------
__global__ void scan_csr(const int* __restrict__ deg, int* __restrict__ rowptr,
                         int* __restrict__ cursor, int n) {
    __shared__ int part[1024];
    int t = threadIdx.x;
    int chunk = (n + 1023) / 1024;
    int base = t * chunk;
    int s = 0;
    for (int i = 0; i < chunk; i++) {
        int id = base + i;
        if (id < n) s += deg[id];
    }
    part[t] = s;
    __syncthreads();
    for (int off = 1; off < 1024; off <<= 1) {
        int v = 0;
        if (t >= off) v = part[t - off];
        __syncthreads();
        part[t] += v;
        __syncthreads();
    }
    int pre = (t == 0) ? 0 : part[t - 1];
    for (int i = 0; i < chunk; i++) {
        int id = base + i;
        if (id < n) {
            rowptr[id] = pre;
            cursor[id] = pre;
            pre += deg[id];
        }
    }
    if (t == 1023) rowptr[n] = part[1023];
}

__global__ void fill_csr(const int* __restrict__ ei, int* __restrict__ cursor,
                         int* __restrict__ elist, int E) {
    int e = blockIdx.x * blockDim.x + threadIdx.x;
    if (e < E) {
        int d = ei[E + e];
        int pos = atomicAdd(&cursor[d], 1);
        elist[pos] = ei[e];   // src
    }
}

// ======================= cooperative per-layer conv =======================
// Phase 1 (ab): Atab = h@W1A + biasA ; Btab = h@W1B + biasB  (grid-stride tiles)
// grid.sync()
// Phase 2 (ec): h[v] = max_e relu(Atab[v]+Btab[src_e]) @ W2 + b2   (in-place)
// ec is the r10 structure: 32x32x16 MFMA, 1-tile/node, af reloaded per tile (L1
// broadcast), one f32x16 acc live at a time (sched_barrier), W2 LDS fragment-major.
__global__ __launch_bounds__(512) void conv_layer(_Float16* __restrict__ h,
                                                  const _Float16* __restrict__ WABT_l,
                                                  const float* __restrict__ biasAB_l,
                                                  const _Float16* __restrict__ W2T_l,
                                                  const float* __restrict__ b2_l,
                                                  const int* __restrict__ rowptr,
                                                  const int* __restrict__ elist,
                                                  _Float16* __restrict__ Atab,
                                                  _Float16* __restrict__ Btab, int n) {
    __shared__ _Float16 w2s[2048 * 8];   // 32 frags (kb*4+cb) x 64 lanes x 16B = 32 KB
    __shared__ float b2s[HID];
    int tid = threadIdx.x;
    // stage W2 (LDS idle during ab; grid.sync provides the block barrier before use)
    #pragma unroll
    for (int i = 0; i < 4; i++) {
        int fid = i * 512 + tid;
        int ln = fid & 63;
        int grp = fid >> 6;
        int kb = grp >> 2;
        int cb = grp & 3;
        *(half8*)(w2s + (size_t)fid * 8) =
            load_h8(W2T_l + (size_t)(cb * 32 + (ln & 31)) * HID + kb * 16 + (ln >> 5) * 8);
    }
    if (tid < HID) b2s[tid] = b2_l[tid];

    int lane = tid & 63;
    int gw = (blockIdx.x * blockDim.x + tid) >> 6;
    int nw = (gridDim.x * blockDim.x) >> 6;

    // ---------- phase 1: ab gemm (grid-stride over nmt*8 tiles) ----------
    {
        int c = lane & 15;
        int kq = lane >> 4;
        int nmt = (n + 15) >> 4;
        for (int tile = gw; tile < nmt * 8; tile += nw) {
            int mt = tile >> 3;
            int jp = tile & 7;
            int arow = mt * 16 + c;
            half8 a[4];
            #pragma unroll
            for (int kb = 0; kb < 4; kb++) {
                if (arow < n) a[kb] = load_h8(h + (size_t)arow * HID + kb * 32 + kq * 8);
                else          a[kb] = (half8)(_Float16)0;
            }
            f32x4 acc[2];
            #pragma unroll
            for (int p = 0; p < 2; p++) {
                acc[p][0] = 0.f; acc[p][1] = 0.f; acc[p][2] = 0.f; acc[p][3] = 0.f;
                int wrow = (jp * 2 + p) * 16 + c;
                #pragma unroll
                for (int kb = 0; kb < 4; kb++) {
                    half8 b = load_h8(WABT_l + (size_t)wrow * HID + kb * 32 + kq * 8);
                    acc[p] = __builtin_amdgcn_mfma_f32_16x16x32_f16(a[kb], b, acc[p], 0, 0, 0);
                }
            }
            #pragma unroll
            for (int p = 0; p < 2; p++) {
                int col = (jp * 2 + p) * 16 + c;
                float bv = biasAB_l[col];
                _Float16* dst = (col < HID) ? Atab : Btab;
                int dcol = col & (HID - 1);
                #pragma unroll
                for (int r = 0; r < 4; r++) {
                    int row = mt * 16 + kq * 4 + r;
                    if (row < n) dst[(size_t)row * HID + dcol] = (_Float16)(acc[p][r] + bv);
                }
            }
        }
    }

    __threadfence();                 // device-scope release of Atab/Btab (cross-XCD)
    cg::this_grid().sync();
    __threadfence();                 // acquire side

    // ---------- phase 2: edge conv ----------
    int er = lane & 31;
    int hi = lane >> 5;
    if (gw >= n) return;

    int v = gw;
    int rbeg0 = rowptr[v];
    int deg0 = rowptr[v + 1] - rbeg0;
    int src0 = (er < deg0) ? elist[rbeg0 + er] : v;
    int v1 = v + nw;
    int rbeg1 = 0, deg1 = 0;
    if (v1 < n) { rbeg1 = rowptr[v1]; deg1 = rowptr[v1 + 1] - rbeg1; }

    while (true) {
        int vn = v + nw;
        int vn2 = vn + nw;
        int rbeg2 = 0, deg2 = 0;
        if (vn2 < n) { rbeg2 = rowptr[vn2]; deg2 = rowptr[vn2 + 1] - rbeg2; }
        int src1 = (er < deg1) ? elist[rbeg1 + er] : vn;

        int ntile = (deg0 + 32) >> 5;        // ceil((deg0+1)/32), pad = self-loop
        float macc0 = -3.0e38f, macc1 = -3.0e38f, macc2 = -3.0e38f, macc3 = -3.0e38f;

        int src = src0;
        for (int tI = 0; tI < ntile; tI++) {
            const _Float16* ap = Atab + (size_t)v * HID + hi * 8;
            const _Float16* bp = Btab + (size_t)src * HID + hi * 8;
            half8 s[8];
            #pragma unroll
            for (int kb = 0; kb < 8; kb++) {
                half8 t2 = load_h8(ap + kb * 16) + load_h8(bp + kb * 16);
                #pragma unroll
                for (int e2 = 0; e2 < 8; e2++) t2[e2] = (t2[e2] > (_Float16)0) ? t2[e2] : (_Float16)0;
                s[kb] = t2;
            }
            int en = (tI + 1) * 32 + er;
            int srcn = (tI + 1 < ntile && en < deg0) ? elist[rbeg0 + en] : v;

#define CB_BLOCK(CB, MREF)                                                              \
            {                                                                           \
                f32x16 d;                                                               \
                _Pragma("unroll")                                                       \
                for (int e2 = 0; e2 < 16; e2++) d[e2] = 0.f;                            \
                _Pragma("unroll")                                                       \
                for (int kb = 0; kb < 8; kb++) {                                        \
                    half8 w = *(const half8*)(w2s + ((size_t)((kb * 4 + CB) * 64 + lane)) * 8); \
                    d = __builtin_amdgcn_mfma_f32_32x32x16_f16(s[kb], w, d, 0, 0, 0);   \
                }                                                                       \
                float m0 = fmaxf(fmaxf(d[0], d[1]), fmaxf(d[2], d[3]));                 \
                float m1 = fmaxf(fmaxf(d[4], d[5]), fmaxf(d[6], d[7]));                 \
                float m2 = fmaxf(fmaxf(d[8], d[9]), fmaxf(d[10], d[11]));               \
                float m3 = fmaxf(fmaxf(d[12], d[13]), fmaxf(d[14], d[15]));             \
                MREF = fmaxf(MREF, fmaxf(fmaxf(m0, m1), fmaxf(m2, m3)));                \
            }
            CB_BLOCK(0, macc0)
            __builtin_amdgcn_sched_barrier(0);
            CB_BLOCK(1, macc1)
            __builtin_amdgcn_sched_barrier(0);
            CB_BLOCK(2, macc2)
            __builtin_amdgcn_sched_barrier(0);
            CB_BLOCK(3, macc3)
#undef CB_BLOCK
            src = srcn;
        }

#define WR(CB, MREF)                                                                    \
        {                                                                               \
            float m = fmaxf(MREF, __shfl_xor(MREF, 32));                                \
            m += b2s[CB * 32 + er];                                                     \
            if (lane < 32) h[(size_t)v * HID + CB * 32 + er] = (_Float16)m;             \
        }
        WR(0, macc0) WR(1, macc1) WR(2, macc2) WR(3, macc3)
#undef WR

        v = vn;
        if (v >= n) break;
        src0 = src1;
        rbeg0 = rbeg1; deg0 = deg1;
        rbeg1 = rbeg2; deg1 = deg2;
    }
}

// ---------------- fallback pair (r10 path, used only if cooperative launch fails) -------
__global__ __launch_bounds__(256) void ab_gemm(const _Float16* __restrict__ A,
                                               const _Float16* __restrict__ WT,
                                               const float* __restrict__ biasAB_l,
                                               _Float16* __restrict__ Atab,
                                               _Float16* __restrict__ Btab, int n) {
    int gw = (blockIdx.x * blockDim.x + threadIdx.x) >> 6;
    int lane = threadIdx.x & 63;
    int nmt = (n + 15) >> 4;
    if (gw >= nmt * 8) return;
    int mt = gw >> 3;
    int jp = gw & 7;
    int c = lane & 15;
    int kq = lane >> 4;

    int arow = mt * 16 + c;
    half8 a[4];
    #pragma unroll
    for (int kb = 0; kb < 4; kb++) {
        if (arow < n) a[kb] = load_h8(A + (size_t)arow * HID + kb * 32 + kq * 8);
        else          a[kb] = (half8)(_Float16)0;
    }
    f32x4 acc[2];
    #pragma unroll
    for (int p = 0; p < 2; p++) {
        acc[p][0] = 0.f; acc[p][1] = 0.f; acc[p][2] = 0.f; acc[p][3] = 0.f;
        int wrow = (jp * 2 + p) * 16 + c;
        #pragma unroll
        for (int kb = 0; kb < 4; kb++) {
            half8 b = load_h8(WT + (size_t)wrow * HID + kb * 32 + kq * 8);
            acc[p] = __builtin_amdgcn_mfma_f32_16x16x32_f16(a[kb], b, acc[p], 0, 0, 0);
        }
    }
    #pragma unroll
    for (int p = 0; p < 2; p++) {
        int col = (jp * 2 + p) * 16 + c;
        float bv = biasAB_l[col];
        _Float16* dst = (col < HID) ? Atab : Btab;
        int dcol = col & (HID - 1);
        #pragma unroll
        for (int r = 0; r < 4; r++) {
            int row = mt * 16 + kq * 4 + r;
            if (row < n) dst[(size_t)row * HID + dcol] = (_Float16)(acc[p][r] + bv);
        }
    }
}

__global__ __launch_bounds__(512) void edge_conv(const _Float16* __restrict__ Atab,
                                                 const _Float16* __restrict__ Btab,
                                                 const _Float16* __restrict__ W2T_l,
                                                 const float* __restrict__ b2_l,
                                                 const int* __restrict__ rowptr,
                                                 const int* __restrict__ elist,
                                                 _Float16* __restrict__ hout, int n) {
    __shared__ _Float16 w2s[2048 * 8];
    __shared__ float b2s[HID];
    int tid = threadIdx.x;
    #pragma unroll
    for (int i = 0; i < 4; i++) {
        int fid = i * 512 + tid;
        int ln = fid & 63;
        int grp = fid >> 6;
        int kb = grp >> 2;
        int cb = grp & 3;
        *(half8*)(w2s + (size_t)fid * 8) =
            load_h8(W2T_l + (size_t)(cb * 32 + (ln & 31)) * HID + kb * 16 + (ln >> 5) * 8);
    }
    if (tid < HID) b2s[tid] = b2_l[tid];
    __syncthreads();

    int lane = tid & 63;
    int er = lane & 31;
    int hi = lane >> 5;
    int gw = (blockIdx.x * blockDim.x + tid) >> 6;
    int nw = (gridDim.x * blockDim.x) >> 6;
    if (gw >= n) return;

    int v = gw;
    int rbeg0 = rowptr[v];
    int deg0 = rowptr[v + 1] - rbeg0;
    int src0 = (er < deg0) ? elist[rbeg0 + er] : v;
    int v1 = v + nw;
    int rbeg1 = 0, deg1 = 0;
    if (v1 < n) { rbeg1 = rowptr[v1]; deg1 = rowptr[v1 + 1] - rbeg1; }

    while (true) {
        int vn = v + nw;
        int vn2 = vn + nw;
        int rbeg2 = 0, deg2 = 0;
        if (vn2 < n) { rbeg2 = rowptr[vn2]; deg2 = rowptr[vn2 + 1] - rbeg2; }
        int src1 = (er < deg1) ? elist[rbeg1 + er] : vn;

        int ntile = (deg0 + 32) >> 5;
        float macc0 = -3.0e38f, macc1 = -3.0e38f, macc2 = -3.0e38f, macc3 = -3.0e38f;

        int src = src0;
        for (int tI = 0; tI < ntile; tI++) {
            const _Float16* ap = Atab + (size_t)v * HID + hi * 8;
            const _Float16* bp = Btab + (size_t)src * HID + hi * 8;
            half8 s[8];
            #pragma unroll
            for (int kb = 0; kb < 8; kb++) {
                half8 t2 = load_h8(ap + kb * 16) + load_h8(bp + kb * 16);
                #pragma unroll
                for (int e2 = 0; e2 < 8; e2++) t2[e2] = (t2[e2] > (_Float16)0) ? t2[e2] : (_Float16)0;
                s[kb] = t2;
            }
            int en = (tI + 1) * 32 + er;
            int srcn = (tI + 1 < ntile && en < deg0) ? elist[rbeg0 + en] : v;

#define CB_BLOCK(CB, MREF)                                                              \
            {                                                                           \
                f32x16 d;                                                               \
                _Pragma("unroll")                                                       \
                for (int e2 = 0; e2 < 16; e2++) d[e2] = 0.f;                            \
                _Pragma("unroll")                                                       \
                for (int kb = 0; kb < 8; kb++) {                                        \
                    half8 w = *(const half8*)(w2s + ((size_t)((kb * 4 + CB) * 64 + lane)) * 8); \
                    d = __builtin_amdgcn_mfma_f32_32x32x16_f16(s[kb], w, d, 0, 0, 0);   \
                }                                                                       \
                float m0 = fmaxf(fmaxf(d[0], d[1]), fmaxf(d[2], d[3]));                 \
                float m1 = fmaxf(fmaxf(d[4], d[5]), fmaxf(d[6], d[7]));                 \
                float m2 = fmaxf(fmaxf(d[8], d[9]), fmaxf(d[10], d[11]));               \
                float m3 = fmaxf(fmaxf(d[12], d[13]), fmaxf(d[14], d[15]));             \
                MREF = fmaxf(MREF, fmaxf(fmaxf(m0, m1), fmaxf(m2, m3)));                \
            }
            CB_BLOCK(0, macc0)
            __builtin_amdgcn_sched_barrier(0);
            CB_BLOCK(1, macc1)
            __builtin_amdgcn_sched_barrier(0);
            CB_BLOCK(2, macc2)
            __builtin_amdgcn_sched_barrier(0);
            CB_BLOCK(3, macc3)
#undef CB_BLOCK
            src = srcn;
        }

#define WR(CB, MREF)                                                                    \
        {                                                                               \
            float m = fmaxf(MREF, __shfl_xor(MREF, 32));                                \
            m += b2s[CB * 32 + er];                                                     \
            if (lane < 32) hout[(size_t)v * HID + CB * 32 + er] = (_Float16)m;          \
        }
        WR(0, macc0) WR(1, macc1) WR(2, macc2) WR(3, macc3)
#undef WR

        v = vn;
        if (v >= n) break;
        src0 = src1;
        rbeg0 = rbeg1; deg0 = deg1;
        rbeg1 = rbeg2; deg1 = deg2;
    }
}

// ---------------- decoder FC via MFMA: out[n][16] = h @ dWT^T + db (f32 out) ------------
__global__ __launch_bounds__(256) void fc_dec_mfma(const _Float16* __restrict__ h16,
                                                   const _Float16* __restrict__ dWT,
                                                   const float* __restrict__ db,
                                                   float* __restrict__ out, int n) {
    int gw = (blockIdx.x * blockDim.x + threadIdx.x) >> 6;
    int lane = threadIdx.x & 63;
    int nmt = (n + 15) >> 4;
    if (gw >= nmt) return;
    int c = lane & 15;
    int kq = lane >> 4;

    int arow = gw * 16 + c;
    f32x4 acc = {0.f, 0.f, 0.f, 0.f};
    #pragma unroll
    for (int kb = 0; kb < 4; kb++) {
        half8 a = (arow < n) ? load_h8(h16 + (size_t)arow * HID + kb * 32 + kq * 8)
                             : (half8)(_Float16)0;
        half8 b = load_h8(dWT + (size_t)c * HID + kb * 32 + kq * 8);
        acc = __builtin_amdgcn_mfma_f32_16x16x32_f16(a, b, acc, 0, 0, 0);
    }
    float bv = db[c];
    #pragma unroll
    for (int r = 0; r < 4; r++) {
        int row = gw * 16 + kq * 4 + r;
        if (row < n) out[(size_t)row * NDIM + c] = acc[r] + bv;
    }
}

// ---------------- host ----------------
extern "C" void kernel_launch(void* const* d_in, const int* in_sizes, int n_in,
                              void* d_out, int out_size, void* d_ws, size_t ws_size,
                              hipStream_t stream) {
    const float* x   = (const float*)d_in[0];
    const int*   ei  = (const int*)d_in[1];
    const float* t   = (const float*)d_in[2];
    const float* neW = (const float*)d_in[3];
    const float* neb = (const float*)d_in[4];
    const float* cW1 = (const float*)d_in[5];
    const float* cb1 = (const float*)d_in[6];
    const float* cW2 = (const float*)d_in[7];
    const float* cb2 = (const float*)d_in[8];
    const float* eW  = (const float*)d_in[9];
    const float* eb  = (const float*)d_in[10];
    const float* dW  = (const float*)d_in[11];
    const float* db  = (const float*)d_in[12];
    const float* tpW = (const float*)d_in[13];
    const float* tpb = (const float*)d_in[14];

    int N = in_sizes[0] / NDIM;
    int E = in_sizes[1] / 2;

    char* w = (char*)d_ws;
    auto alloc = [&](size_t bytes) {
        void* p = (void*)w;
        w += (bytes + 255) & ~(size_t)255;
        return p;
    };
    _Float16*  hA     = (_Float16*)alloc((size_t)N * HID * 2);
    _Float16*  Atab   = (_Float16*)alloc((size_t)N * HID * 2);
    _Float16*  Btab   = (_Float16*)alloc((size_t)N * HID * 2);
    _Float16*  WABT   = (_Float16*)alloc((size_t)NCONV * 2 * HID * HID * 2);
    _Float16*  W2T    = (_Float16*)alloc((size_t)NCONV * HID * HID * 2);
    _Float16*  dWT    = (_Float16*)alloc((size_t)16 * HID * 2);
    float*     biasAB = (float*)alloc((size_t)NCONV * 256 * 4);
    int*       deg    = (int*)alloc((size_t)N * 4);
    int*       rowptr = (int*)alloc((size_t)(N + 1) * 4);
    int*       cursor = (int*)alloc((size_t)N * 4);
    int*       elist  = (int*)alloc((size_t)E * 4);

    // 1: weights + biasAB + zero deg
    int prep_total = NCONV * HID * HID + 16 * HID + NCONV * 256 + N;
    prep_weights<<<(prep_total + 255) / 256, 256, 0, stream>>>(cW1, cW2, dW, cb1,
                                                               WABT, W2T, dWT, biasAB, deg, N);
    // 2: fold enc_fc into layer-4 ab weights (overwrites WABT[4], biasAB[4])
    enc_fold<<<(2 * HID * HID + 256 + 255) / 256, 256, 0, stream>>>(cW1, eW, eb, cb1,
                                                                    WABT, biasAB);
    // 3: node embedding + degree count
    node_emb_count<<<1024, 256, 0, stream>>>(x, t, tpW, tpb, neW, neb, ei, deg, hA, N, E);
    // 4-5: CSR
    scan_csr<<<1, 1024, 0, stream>>>(deg, rowptr, cursor, N);
    fill_csr<<<(E + 255) / 256, 256, 0, stream>>>(ei, cursor, elist, E);

    // cooperative grid sizing (runtime occupancy query; deterministic)
    int maxb = 0;
    hipError_t qerr = hipOccupancyMaxActiveBlocksPerMultiprocessor(&maxb, conv_layer, 512, 0);
    int cgrid = 512;
    bool use_coop = (qerr == hipSuccess && maxb >= 1);
    if (use_coop && maxb * 256 < 512) cgrid = maxb * 256;

    int nmt = (N + 15) / 16;
    int ab_blocks = (nmt * 8 + 3) / 4;
    int ec_blocks = 512;

    for (int l = 0; l < NCONV; l++) {
        const _Float16* wab_l = WABT + (size_t)l * 2 * HID * HID;
        const float*    bab_l = biasAB + (size_t)l * 256;
        const _Float16* w2t_l = W2T + (size_t)l * HID * HID;
        const float*    b2_l  = cb2 + (size_t)l * HID;
        if (use_coop) {
            _Float16* h_ = hA;
            const int* rp_ = rowptr;
            const int* el_ = elist;
            _Float16* at_ = Atab;
            _Float16* bt_ = Btab;
            int n_ = N;
            void* kargs[] = {(void*)&h_, (void*)&wab_l, (void*)&bab_l, (void*)&w2t_l,
                             (void*)&b2_l, (void*)&rp_, (void*)&el_, (void*)&at_,
                             (void*)&bt_, (void*)&n_};
            hipError_t le = hipLaunchCooperativeKernel((void*)conv_layer, dim3(cgrid),
                                                       dim3(512), kargs, 0, stream);
            if (le == hipSuccess) continue;
            use_coop = false;   // fall through to two-kernel path for this & later layers
        }
        ab_gemm<<<ab_blocks, 256, 0, stream>>>(hA, wab_l, bab_l, Atab, Btab, N);
        edge_conv<<<ec_blocks, 512, 0, stream>>>(Atab, Btab, w2t_l, b2_l, rowptr, elist, hA, N);
    }

    fc_dec_mfma<<<(nmt + 3) / 4, 256, 0, stream>>>(hA, dWT, db, (float*)d_out, N);
}

// Round 12
// 292.897 us; speedup vs baseline: 4.2519x; 4.2519x over previous
//
#include <hip/hip_runtime.h>
#include <hip/hip_fp16.h>

typedef _Float16 half8 __attribute__((ext_vector_type(8)));
typedef float f32x4 __attribute__((ext_vector_type(4)));
typedef float f32x16 __attribute__((ext_vector_type(16)));

#define HID 128
#define NDIM 16
#define NCONV 8

static __device__ __forceinline__ half8 load_h8(const _Float16* p) {
    return *(const half8*)p;
}

// ---------------- weight prep ----------------
// WABT[l] rows j<128: W1A_T[j][k]=W1[k][j]-W1[128+k][j]; rows 128+j: W1B_T[j][k]=W1[128+k][j]
// W2T[l][j][k] = W2[k][j].  Tails: dWT[j][k]=dW[k*16+j]; biasAB[l][0:128]=b1_l, [128:256]=0;
// deg[] zeroed (CSR count runs next dispatch).
__global__ void prep_weights(const float* __restrict__ W1, const float* __restrict__ W2,
                             const float* __restrict__ dW, const float* __restrict__ b1,
                             _Float16* __restrict__ WABT, _Float16* __restrict__ W2T,
                             _Float16* __restrict__ dWT, float* __restrict__ biasAB,
                             int* __restrict__ deg, int n) {
    int idx = blockIdx.x * blockDim.x + threadIdx.x;
    int total = NCONV * HID * HID;
    if (idx < total) {
        int l = idx / (HID * HID);
        int r = idx % (HID * HID);
        int k = r / HID;        // slow: input row
        int j = r % HID;        // fast: input col -> coalesced loads
        const float* w1 = W1 + (size_t)l * 2 * HID * HID;
        float top = w1[k * HID + j];
        float bot = w1[(HID + k) * HID + j];
        _Float16* wab = WABT + (size_t)l * 2 * HID * HID;
        wab[j * HID + k] = (_Float16)(top - bot);
        wab[(HID + j) * HID + k] = (_Float16)bot;
        const float* w2 = W2 + (size_t)l * HID * HID;
        W2T[(size_t)l * HID * HID + j * HID + k] = (_Float16)w2[k * HID + j];
    } else if (idx < total + 16 * HID) {
        int r = idx - total;
        int j = r / HID;        // 0..15
        int k = r % HID;
        dWT[j * HID + k] = (_Float16)dW[k * NDIM + j];
    } else if (idx < total + 16 * HID + NCONV * 256) {
        int r = idx - total - 16 * HID;
        int l = r >> 8;
        int c = r & 255;
        biasAB[l * 256 + c] = (c < HID) ? b1[l * HID + c] : 0.f;
    } else if (idx < total + 16 * HID + NCONV * 256 + n) {
        deg[idx - total - 16 * HID - NCONV * 256] = 0;
    }
}

// ---------------- enc fold: layer 4 ab weights absorb enc_fc ----------------
// (h@E+eb)@W1 + b1 == h@(E@W1) + (eb@W1 + b1)
__global__ void enc_fold(const float* __restrict__ W1, const float* __restrict__ eW,
                         const float* __restrict__ eb, const float* __restrict__ b1,
                         _Float16* __restrict__ WABT, float* __restrict__ biasAB) {
    int idx = blockIdx.x * blockDim.x + threadIdx.x;
    const float* w1 = W1 + (size_t)4 * 2 * HID * HID;   // layer 4
    _Float16* wab = WABT + (size_t)4 * 2 * HID * HID;
    if (idx < HID * HID) {
        int k = idx / HID;
        int j = idx % HID;
        float acc = 0.f;
        for (int q = 0; q < HID; q++)
            acc += eW[k * HID + q] * (w1[q * HID + j] - w1[(HID + q) * HID + j]);
        wab[j * HID + k] = (_Float16)acc;
    } else if (idx < 2 * HID * HID) {
        int r = idx - HID * HID;
        int k = r / HID;
        int j = r % HID;
        float acc = 0.f;
        for (int q = 0; q < HID; q++)
            acc += eW[k * HID + q] * w1[(HID + q) * HID + j];
        wab[(HID + j) * HID + k] = (_Float16)acc;
    } else if (idx < 2 * HID * HID + 256) {
        int c = idx - 2 * HID * HID;
        if (c < HID) {
            float acc = b1[4 * HID + c];
            for (int q = 0; q < HID; q++)
                acc += eb[q] * (w1[q * HID + c] - w1[(HID + q) * HID + c]);
            biasAB[4 * 256 + c] = acc;
        } else {
            int j = c - HID;
            float acc = 0.f;
            for (int q = 0; q < HID; q++)
                acc += eb[q] * w1[(HID + q) * HID + j];
            biasAB[4 * 256 + c] = acc;
        }
    }
}

// ---------------- node embedding (time emb fused) + CSR degree count ----------------
__global__ __launch_bounds__(256) void node_emb_count(const float* __restrict__ x,
                                                      const float* __restrict__ t,
                                                      const float* __restrict__ tpW,
                                                      const float* __restrict__ tpb,
                                                      const float* __restrict__ W,
                                                      const float* __restrict__ b,
                                                      const int* __restrict__ ei,
                                                      int* __restrict__ deg,
                                                      _Float16* __restrict__ h16,
                                                      int n, int E) {
    __shared__ float sc[64];
    __shared__ float temb[NDIM];
    int tid = threadIdx.x;
    float tv = t[0];
    if (tid < 32) {
        float f = expf(-4.0f + 8.0f * (float)tid / 31.0f);
        sc[tid] = sinf(tv * f);
        sc[32 + tid] = cosf(tv * f);
    }
    __syncthreads();
    if (tid < 16) {
        float acc = tpb[tid];
        for (int k = 0; k < 64; k++) acc += sc[k] * tpW[k * NDIM + tid];
        temb[tid] = acc;
    }
    __syncthreads();
    int j = tid & 127;
    int half = tid >> 7;
    for (int base = blockIdx.x * 2; base < n; base += gridDim.x * 2) {
        int node = base + half;
        if (node < n) {
            const float* xr = x + (size_t)node * NDIM;
            float acc = b[j];
            #pragma unroll
            for (int d = 0; d < NDIM; d++) acc += (xr[d] + temb[d]) * W[d * HID + j];
            h16[(size_t)node * HID + j] = (_Float16)acc;
        }
    }
    int gtid = blockIdx.x * blockDim.x + tid;
    int gsz = gridDim.x * blockDim.x;
    for (int e = gtid; e < E; e += gsz) atomicAdd(&deg[ei[E + e]], 1);
}

// ---------------- CSR scan / fill ----------------
__global__ void scan_csr(const int* __restrict__ deg, int* __restrict__ rowptr,
                         int* __restrict__ cursor, int n) {
    __shared__ int part[1024];
    int t = threadIdx.x;
    int chunk = (n + 1023) / 1024;
    int base = t * chunk;
    int s = 0;
    for (int i = 0; i < chunk; i++) {
        int id = base + i;
        if (id < n) s += deg[id];
    }
    part[t] = s;
    __syncthreads();
    for (int off = 1; off < 1024; off <<= 1) {
        int v = 0;
        if (t >= off) v = part[t - off];
        __syncthreads();
        part[t] += v;
        __syncthreads();
    }
    int pre = (t == 0) ? 0 : part[t - 1];
    for (int i = 0; i < chunk; i++) {
        int id = base + i;
        if (id < n) {
            rowptr[id] = pre;
            cursor[id] = pre;
            pre += deg[id];
        }
    }
    if (t == 1023) rowptr[n] = part[1023];
}

__global__ void fill_csr(const int* __restrict__ ei, int* __restrict__ cursor,
                         int* __restrict__ elist, int E) {
    int e = blockIdx.x * blockDim.x + threadIdx.x;
    if (e < E) {
        int d = ei[E + e];
        int pos = atomicAdd(&cursor[d], 1);
        elist[pos] = ei[e];   // src
    }
}

// ---------------- ab gemm (layer 0 only): Atab = h@W1A + b1 ; Btab = h@W1B ----------------
__global__ __launch_bounds__(256) void ab_gemm(const _Float16* __restrict__ A,
                                               const _Float16* __restrict__ WT,
                                               const float* __restrict__ biasAB_l,
                                               _Float16* __restrict__ Atab,
                                               _Float16* __restrict__ Btab, int n) {
    int gw = (blockIdx.x * blockDim.x + threadIdx.x) >> 6;
    int lane = threadIdx.x & 63;
    int nmt = (n + 15) >> 4;
    if (gw >= nmt * 8) return;
    int mt = gw >> 3;
    int jp = gw & 7;
    int c = lane & 15;
    int kq = lane >> 4;

    int arow = mt * 16 + c;
    half8 a[4];
    #pragma unroll
    for (int kb = 0; kb < 4; kb++) {
        if (arow < n) a[kb] = load_h8(A + (size_t)arow * HID + kb * 32 + kq * 8);
        else          a[kb] = (half8)(_Float16)0;
    }
    f32x4 acc[2];
    #pragma unroll
    for (int p = 0; p < 2; p++) {
        acc[p][0] = 0.f; acc[p][1] = 0.f; acc[p][2] = 0.f; acc[p][3] = 0.f;
        int wrow = (jp * 2 + p) * 16 + c;
        #pragma unroll
        for (int kb = 0; kb < 4; kb++) {
            half8 b = load_h8(WT + (size_t)wrow * HID + kb * 32 + kq * 8);
            acc[p] = __builtin_amdgcn_mfma_f32_16x16x32_f16(a[kb], b, acc[p], 0, 0, 0);
        }
    }
    #pragma unroll
    for (int p = 0; p < 2; p++) {
        int col = (jp * 2 + p) * 16 + c;
        float bv = biasAB_l[col];
        _Float16* dst = (col < HID) ? Atab : Btab;
        int dcol = col & (HID - 1);
        #pragma unroll
        for (int r = 0; r < 4; r++) {
            int row = mt * 16 + kq * 4 + r;
            if (row < n) dst[(size_t)row * HID + dcol] = (_Float16)(acc[p][r] + bv);
        }
    }
}

// ======================= fused ec_l + ab_{l+1} (or + fc_dec if last) =======================
// 1024-thread block = 16 waves handles groups of 16 nodes:
//   ec: wave w computes h[g*16+w] from (Acur, Bcur) — r10 structure (32x32x16 MFMA,
//       1 tile/node [P(deg>31)~1e-4], af reload per tile, single live f32x16 acc,
//       W2 LDS fragment-major: 0 conflicts) — and writes the row into LDS.
//   barrier; ab: the 16 waves each compute one 16-col j-tile of the group's 16x256
//       ab GEMM for layer l+1, A-fragments straight from LDS (row stride 136 elem:
//       rows land 4 banks apart -> <=2-way, free).  last=1: wave 0 does fc_dec's
//       16x16x32 MFMA instead and writes f32 out.
// No global h traffic for intermediate layers. NO grid.sync anywhere (r11 lesson:
// cooperative grid-sync costs ~200 us on MI355X).
__global__ __launch_bounds__(1024) void fused_conv(const _Float16* __restrict__ Acur,
                                                   const _Float16* __restrict__ Bcur,
                                                   const _Float16* __restrict__ W2T_l,
                                                   const float* __restrict__ b2_l,
                                                   const int* __restrict__ rowptr,
                                                   const int* __restrict__ elist,
                                                   const _Float16* __restrict__ WABT_n,
                                                   const float* __restrict__ biasAB_n,
                                                   _Float16* __restrict__ Anxt,
                                                   _Float16* __restrict__ Bnxt,
                                                   const _Float16* __restrict__ dWT,
                                                   const float* __restrict__ db,
                                                   float* __restrict__ out,
                                                   int last, int n) {
    __shared__ _Float16 w2s[2048 * 8];     // 32 KB, fragment-major
    __shared__ float b2s[HID];
    __shared__ _Float16 hlds[16][136];     // group h rows; stride 272 B (16-mult, 4-bank skew)

    int tid = threadIdx.x;
    #pragma unroll
    for (int i = 0; i < 2; i++) {
        int fid = i * 1024 + tid;          // 0..2047
        int ln = fid & 63;
        int grp = fid >> 6;                // kb*4+cb
        int kb = grp >> 2;
        int cb = grp & 3;
        *(half8*)(w2s + (size_t)fid * 8) =
            load_h8(W2T_l + (size_t)(cb * 32 + (ln & 31)) * HID + kb * 16 + (ln >> 5) * 8);
    }
    if (tid < HID) b2s[tid] = b2_l[tid];
    __syncthreads();

    int lane = tid & 63;
    int wv = tid >> 6;          // wave index 0..15 = node within group
    int er = lane & 31;
    int hi = lane >> 5;
    int c = lane & 15;
    int kq = lane >> 4;

    int ngroups = (n + 15) >> 4;
    int g = blockIdx.x;

    // prologue: group g's rowptr + first-tile srcs
    int v = g * 16 + wv;
    int rbeg = 0, dg = 0;
    if (g < ngroups && v < n) { rbeg = rowptr[v]; dg = rowptr[v + 1] - rbeg; }
    int src0 = (er < dg) ? elist[rbeg + er] : v;

    while (g < ngroups) {
        // prefetch next group's rowptr (consumed next iteration)
        int gn = g + gridDim.x;
        int vN = gn * 16 + wv;
        int rbegN = 0, dgN = 0;
        if (gn < ngroups && vN < n) { rbegN = rowptr[vN]; dgN = rowptr[vN + 1] - rbegN; }

        // ---------- ec phase: this wave's node ----------
        float macc0 = -3.0e38f, macc1 = -3.0e38f, macc2 = -3.0e38f, macc3 = -3.0e38f;
        if (v < n) {
            int ntile = (dg + 32) >> 5;    // ceil((dg+1)/32), pad = self-loop
            int src = src0;
            for (int tI = 0; tI < ntile; tI++) {
                const _Float16* ap = Acur + (size_t)v * HID + hi * 8;
                const _Float16* bp = Bcur + (size_t)src * HID + hi * 8;
                half8 s[8];
                #pragma unroll
                for (int kb = 0; kb < 8; kb++) {
                    half8 t2 = load_h8(ap + kb * 16) + load_h8(bp + kb * 16);
                    #pragma unroll
                    for (int e2 = 0; e2 < 8; e2++) t2[e2] = (t2[e2] > (_Float16)0) ? t2[e2] : (_Float16)0;
                    s[kb] = t2;
                }
                int en = (tI + 1) * 32 + er;
                int srcn = (tI + 1 < ntile && en < dg) ? elist[rbeg + en] : v;

#define CB_BLOCK(CB, MREF)                                                              \
                {                                                                       \
                    f32x16 d;                                                           \
                    _Pragma("unroll")                                                   \
                    for (int e2 = 0; e2 < 16; e2++) d[e2] = 0.f;                        \
                    _Pragma("unroll")                                                   \
                    for (int kb = 0; kb < 8; kb++) {                                    \
                        half8 w = *(const half8*)(w2s + ((size_t)((kb * 4 + CB) * 64 + lane)) * 8); \
                        d = __builtin_amdgcn_mfma_f32_32x32x16_f16(s[kb], w, d, 0, 0, 0); \
                    }                                                                   \
                    float m0 = fmaxf(fmaxf(d[0], d[1]), fmaxf(d[2], d[3]));             \
                    float m1 = fmaxf(fmaxf(d[4], d[5]), fmaxf(d[6], d[7]));             \
                    float m2 = fmaxf(fmaxf(d[8], d[9]), fmaxf(d[10], d[11]));           \
                    float m3 = fmaxf(fmaxf(d[12], d[13]), fmaxf(d[14], d[15]));         \
                    MREF = fmaxf(MREF, fmaxf(fmaxf(m0, m1), fmaxf(m2, m3)));            \
                }
                CB_BLOCK(0, macc0)
                __builtin_amdgcn_sched_barrier(0);
                CB_BLOCK(1, macc1)
                __builtin_amdgcn_sched_barrier(0);
                CB_BLOCK(2, macc2)
                __builtin_amdgcn_sched_barrier(0);
                CB_BLOCK(3, macc3)
#undef CB_BLOCK
                src = srcn;
            }
        }

        // prefetch next group's first-tile srcs (rowptr arrived by now)
        int srcN = (er < dgN) ? elist[rbegN + er] : vN;

        // merge k-halves, write h row to LDS
        {
            float m0 = fmaxf(macc0, __shfl_xor(macc0, 32)) + b2s[er];
            float m1 = fmaxf(macc1, __shfl_xor(macc1, 32)) + b2s[32 + er];
            float m2 = fmaxf(macc2, __shfl_xor(macc2, 32)) + b2s[64 + er];
            float m3 = fmaxf(macc3, __shfl_xor(macc3, 32)) + b2s[96 + er];
            if (lane < 32) {
                hlds[wv][er]      = (_Float16)m0;
                hlds[wv][32 + er] = (_Float16)m1;
                hlds[wv][64 + er] = (_Float16)m2;
                hlds[wv][96 + er] = (_Float16)m3;
            }
        }
        __syncthreads();

        int gbase = g * 16;
        if (!last) {
            // ---------- ab phase for layer l+1: wave wv -> j-tile wv ----------
            half8 a[4];
            #pragma unroll
            for (int kb = 0; kb < 4; kb++)
                a[kb] = load_h8(&hlds[c][kb * 32 + kq * 8]);
            f32x4 acc = {0.f, 0.f, 0.f, 0.f};
            int wrow = wv * 16 + c;        // output col 0..255
            #pragma unroll
            for (int kb = 0; kb < 4; kb++) {
                half8 b = load_h8(WABT_n + (size_t)wrow * HID + kb * 32 + kq * 8);
                acc = __builtin_amdgcn_mfma_f32_16x16x32_f16(a[kb], b, acc, 0, 0, 0);
            }
            float bv = biasAB_n[wrow];
            _Float16* dst = (wrow < HID) ? Anxt : Bnxt;
            int dcol = wrow & (HID - 1);
            #pragma unroll
            for (int r = 0; r < 4; r++) {
                int row = gbase + kq * 4 + r;
                if (row < n) dst[(size_t)row * HID + dcol] = (_Float16)(acc[r] + bv);
            }
        } else if (wv == 0) {
            // ---------- fc_dec: out[g*16..+16][16] = h @ dWT^T + db ----------
            half8 a[4];
            #pragma unroll
            for (int kb = 0; kb < 4; kb++)
                a[kb] = load_h8(&hlds[c][kb * 32 + kq * 8]);
            f32x4 acc = {0.f, 0.f, 0.f, 0.f};
            #pragma unroll
            for (int kb = 0; kb < 4; kb++) {
                half8 b = load_h8(dWT + (size_t)c * HID + kb * 32 + kq * 8);
                acc = __builtin_amdgcn_mfma_f32_16x16x32_f16(a[kb], b, acc, 0, 0, 0);
            }
            float bv = db[c];
            #pragma unroll
            for (int r = 0; r < 4; r++) {
                int row = gbase + kq * 4 + r;
                if (row < n) out[(size_t)row * NDIM + c] = acc[r] + bv;
            }
        }
        __syncthreads();   // hlds safe to overwrite next iteration

        // rotate group window
        g = gn;
        v = vN;
        rbeg = rbegN; dg = dgN;
        src0 = srcN;
    }
}

// ---------------- host ----------------
extern "C" void kernel_launch(void* const* d_in, const int* in_sizes, int n_in,
                              void* d_out, int out_size, void* d_ws, size_t ws_size,
                              hipStream_t stream) {
    const float* x   = (const float*)d_in[0];
    const int*   ei  = (const int*)d_in[1];
    const float* t   = (const float*)d_in[2];
    const float* neW = (const float*)d_in[3];
    const float* neb = (const float*)d_in[4];
    const float* cW1 = (const float*)d_in[5];
    const float* cb1 = (const float*)d_in[6];
    const float* cW2 = (const float*)d_in[7];
    const float* cb2 = (const float*)d_in[8];
    const float* eW  = (const float*)d_in[9];
    const float* eb  = (const float*)d_in[10];
    const float* dW  = (const float*)d_in[11];
    const float* db  = (const float*)d_in[12];
    const float* tpW = (const float*)d_in[13];
    const float* tpb = (const float*)d_in[14];

    int N = in_sizes[0] / NDIM;
    int E = in_sizes[1] / 2;

    char* w = (char*)d_ws;
    auto alloc = [&](size_t bytes) {
        void* p = (void*)w;
        w += (bytes + 255) & ~(size_t)255;
        return p;
    };
    _Float16*  hA     = (_Float16*)alloc((size_t)N * HID * 2);
    _Float16*  Atab0  = (_Float16*)alloc((size_t)N * HID * 2);
    _Float16*  Btab0  = (_Float16*)alloc((size_t)N * HID * 2);
    _Float16*  Atab1  = (_Float16*)alloc((size_t)N * HID * 2);
    _Float16*  Btab1  = (_Float16*)alloc((size_t)N * HID * 2);
    _Float16*  WABT   = (_Float16*)alloc((size_t)NCONV * 2 * HID * HID * 2);
    _Float16*  W2T    = (_Float16*)alloc((size_t)NCONV * HID * HID * 2);
    _Float16*  dWT    = (_Float16*)alloc((size_t)16 * HID * 2);
    float*     biasAB = (float*)alloc((size_t)NCONV * 256 * 4);
    int*       deg    = (int*)alloc((size_t)N * 4);
    int*       rowptr = (int*)alloc((size_t)(N + 1) * 4);
    int*       cursor = (int*)alloc((size_t)N * 4);
    int*       elist  = (int*)alloc((size_t)E * 4);

    int prep_total = NCONV * HID * HID + 16 * HID + NCONV * 256 + N;
    prep_weights<<<(prep_total + 255) / 256, 256, 0, stream>>>(cW1, cW2, dW, cb1,
                                                               WABT, W2T, dWT, biasAB, deg, N);
    enc_fold<<<(2 * HID * HID + 256 + 255) / 256, 256, 0, stream>>>(cW1, eW, eb, cb1,
                                                                    WABT, biasAB);
    node_emb_count<<<1024, 256, 0, stream>>>(x, t, tpW, tpb, neW, neb, ei, deg, hA, N, E);
    scan_csr<<<1, 1024, 0, stream>>>(deg, rowptr, cursor, N);
    fill_csr<<<(E + 255) / 256, 256, 0, stream>>>(ei, cursor, elist, E);

    int nmt = (N + 15) / 16;
    ab_gemm<<<(nmt * 8 + 3) / 4, 256, 0, stream>>>(hA, WABT, biasAB, Atab0, Btab0, N);

    for (int l = 0; l < NCONV; l++) {
        const _Float16* Acur = (l & 1) ? Atab1 : Atab0;
        const _Float16* Bcur = (l & 1) ? Btab1 : Btab0;
        _Float16* Anxt = (l & 1) ? Atab0 : Atab1;
        _Float16* Bnxt = (l & 1) ? Btab0 : Btab1;
        int ln = (l + 1 < NCONV) ? (l + 1) : 0;   // dummy (unused) when last
        fused_conv<<<512, 1024, 0, stream>>>(Acur, Bcur,
                                             W2T + (size_t)l * HID * HID,
                                             cb2 + (size_t)l * HID,
                                             rowptr, elist,
                                             WABT + (size_t)ln * 2 * HID * HID,
                                             biasAB + (size_t)ln * 256,
                                             Anxt, Bnxt,
                                             dWT, db, (float*)d_out,
                                             (l == NCONV - 1) ? 1 : 0, N);
    }
}